// Round 6
// baseline (338.529 us; speedup 1.0000x reference)
//
#include <hip/hip_runtime.h>
#include <hip/hip_bf16.h>
#include <stdint.h>

typedef __attribute__((ext_vector_type(8))) short short8;
typedef __attribute__((ext_vector_type(4))) float floatx4;
typedef __attribute__((ext_vector_type(8))) int int8v;
typedef __attribute__((ext_vector_type(4))) int int4v;

__device__ __forceinline__ ushort f2b(float f) {
    union { float f; uint32_t u; } v; v.f = f;
    uint32_t r = (v.u + 0x7fffu + ((v.u >> 16) & 1u)) >> 16;
    return (ushort)r;
}
__device__ __forceinline__ float b2f(ushort b) {
    union { uint32_t u; float f; } v; v.u = ((uint32_t)b) << 16;
    return v.f;
}
__device__ __forceinline__ uint8_t f2fp8(float f) {
    return (uint8_t)(__builtin_amdgcn_cvt_pk_fp8_f32(f, f, 0, false) & 0xff);
}

__device__ __forceinline__ void gl_lds16(const void* g, void* l) {
    __builtin_amdgcn_global_load_lds(
        (const __attribute__((address_space(1))) void*)g,
        (__attribute__((address_space(3))) void*)l, 16, 0, 0);
}

// ---------------- elementwise f32 -> bf16 ----------------
__global__ __launch_bounds__(256) void convert_f32_bf16(const float* __restrict__ in,
                                                        ushort* __restrict__ out, int n4) {
    int i = blockIdx.x * 256 + threadIdx.x;
    if (i < n4) {
        float4 v = ((const float4*)in)[i];
        ushort4 o;
        o.x = f2b(v.x); o.y = f2b(v.y); o.z = f2b(v.z); o.w = f2b(v.w);
        ((ushort4*)out)[i] = o;
    }
}

// ---------------- elementwise f32 -> fp8 e4m3 (*s) ----------------
__global__ __launch_bounds__(256) void convert_f32_fp8(const float* __restrict__ in,
                                                       uint8_t* __restrict__ out,
                                                       int n4, float s) {
    int i = blockIdx.x * 256 + threadIdx.x;
    if (i < n4) {
        float4 v = ((const float4*)in)[i];
        int p = __builtin_amdgcn_cvt_pk_fp8_f32(v.x * s, v.y * s, 0, false);
        p = __builtin_amdgcn_cvt_pk_fp8_f32(v.z * s, v.w * s, p, true);
        ((uint32_t*)out)[i] = p;
    }
}

// ---------------- transpose f32[R,C] -> bf16[C,R] ----------------
__global__ __launch_bounds__(256) void transpose_f32_to_bf16(const float* __restrict__ in,
                                                             ushort* __restrict__ out,
                                                             int R, int Cc) {
    __shared__ ushort t[32][33];
    int bx = blockIdx.x * 32, by = blockIdx.y * 32;
    int tx = threadIdx.x & 31, ty = threadIdx.x >> 5;
    #pragma unroll
    for (int i = 0; i < 32; i += 8)
        t[ty + i][tx] = f2b(in[(size_t)(by + ty + i) * Cc + bx + tx]);
    __syncthreads();
    #pragma unroll
    for (int i = 0; i < 32; i += 8)
        out[(size_t)(bx + ty + i) * R + by + tx] = t[tx][ty + i];
}

// ---------------- transpose bf16[R,C] -> bf16[C,R] ----------------
__global__ __launch_bounds__(256) void transpose_bf16(const ushort* __restrict__ in,
                                                      ushort* __restrict__ out,
                                                      int R, int Cc) {
    __shared__ ushort t[32][33];
    int bx = blockIdx.x * 32, by = blockIdx.y * 32;
    int tx = threadIdx.x & 31, ty = threadIdx.x >> 5;
    #pragma unroll
    for (int i = 0; i < 32; i += 8)
        t[ty + i][tx] = in[(size_t)(by + ty + i) * Cc + bx + tx];
    __syncthreads();
    #pragma unroll
    for (int i = 0; i < 32; i += 8)
        out[(size_t)(bx + ty + i) * R + by + tx] = t[tx][ty + i];
}

// ---------------- row L2-normalize f32 in -> bf16 out ----------------
__global__ __launch_bounds__(256) void normalize_f32_to_bf16(const float* __restrict__ in,
                                                             ushort* __restrict__ out, int D) {
    int row = blockIdx.x;
    const float* x = in + (size_t)row * D;
    float s = 0.0f;
    for (int i = threadIdx.x; i < D; i += 256) { float t = x[i]; s += t * t; }
    __shared__ float sm[4];
    #pragma unroll
    for (int off = 32; off; off >>= 1) s += __shfl_down(s, off, 64);
    if ((threadIdx.x & 63) == 0) sm[threadIdx.x >> 6] = s;
    __syncthreads();
    float inv = 1.0f / sqrtf(sm[0] + sm[1] + sm[2] + sm[3]);
    ushort* o = out + (size_t)row * D;
    for (int i = threadIdx.x; i < D; i += 256) o[i] = f2b(x[i] * inv);
}

// ======== bf16 MFMA GEMM core (m97 structure), templated epilogue ========
// MODE 0: bf16 out = scale*acc      MODE 1: fp8 out = f2fp8(64*acc) + rn sumsq atomic
template<int MODE>
__global__ __launch_bounds__(256, 4) void gemm_bt(
    const ushort* __restrict__ A, const ushort* __restrict__ B,
    float* __restrict__ rn, void* __restrict__ Co,
    int M, int N, int K, float scale)
{
    __shared__ alignas(16) ushort As[128 * 32];
    __shared__ alignas(16) ushort Bs[128 * 32];
    const int id = threadIdx.x;
    const int wave = id >> 6, lane = id & 63;

    int bxi = blockIdx.x, byi = blockIdx.y;
    if ((gridDim.y & 7) == 0) {
        int i = byi * gridDim.x + bxi;
        int xcd = i & 7;
        int j = i >> 3;
        bxi = j % gridDim.x;
        byi = xcd + 8 * (j / gridDim.x);
    }
    const int row0 = byi * 128, col0 = bxi * 128;
    const int wm = (wave >> 1) * 64, wn = (wave & 1) * 64;

    const int f0 = id, f1 = id + 256;
    const int ar0 = f0 >> 2, as0 = (f0 & 3) * 8;
    const int ar1 = f1 >> 2, as1 = (f1 & 3) * 8;

    const ushort* Ag0 = A + (size_t)(row0 + ar0) * K + as0;
    const ushort* Ag1 = A + (size_t)(row0 + ar1) * K + as1;
    const ushort* Bg0 = B + (size_t)(col0 + ar0) * K + as0;
    const ushort* Bg1 = B + (size_t)(col0 + ar1) * K + as1;

    floatx4 acc[4][4] = {};
    const int mrow = lane & 15, koff = (lane >> 4) * 8;

    for (int k0 = 0; k0 < K; k0 += 32) {
        gl_lds16(Ag0 + k0, &As[f0 * 8]);
        gl_lds16(Ag1 + k0, &As[f1 * 8]);
        gl_lds16(Bg0 + k0, &Bs[f0 * 8]);
        gl_lds16(Bg1 + k0, &Bs[f1 * 8]);
        __syncthreads();
        short8 a[4], b[4];
        #pragma unroll
        for (int i = 0; i < 4; i++)
            a[i] = *(const short8*)&As[(wm + i * 16 + mrow) * 32 + koff];
        #pragma unroll
        for (int j = 0; j < 4; j++)
            b[j] = *(const short8*)&Bs[(wn + j * 16 + mrow) * 32 + koff];
        #pragma unroll
        for (int i = 0; i < 4; i++)
            #pragma unroll
            for (int j = 0; j < 4; j++)
                acc[i][j] = __builtin_amdgcn_mfma_f32_16x16x32_bf16(a[i], b[j], acc[i][j], 0, 0, 0);
        __syncthreads();
    }

    // C/D layout: col = lane&15, row = (lane>>4)*4 + r  [m89/m91-verified]
    const int ccol0 = col0 + wn + (lane & 15);
    const int crow0 = row0 + wm + (lane >> 4) * 4;
    #pragma unroll
    for (int i = 0; i < 4; i++) {
        #pragma unroll
        for (int r = 0; r < 4; r++) {
            const int row = crow0 + i * 16 + r;
            float ss = 0.0f;
            #pragma unroll
            for (int j = 0; j < 4; j++) {
                int col = ccol0 + j * 16;
                if constexpr (MODE == 0) {
                    ((ushort*)Co)[(size_t)row * N + col] = f2b(acc[i][j][r] * scale);
                } else {
                    float vq = acc[i][j][r] * 64.0f;     // store 64*summary (fp8)
                    ss += vq * vq;
                    ((uint8_t*)Co)[(size_t)row * N + col] = f2fp8(vq);
                }
            }
            if constexpr (MODE == 1) {
                #pragma unroll
                for (int m = 1; m < 16; m <<= 1) ss += __shfl_xor(ss, m, 64);
                if ((lane & 15) == 0) atomicAdd(&rn[row], ss);
            }
        }
    }
}

// ------------- fused concept GEMMs (bf16): kmat=c@Wk^T (bf16 out), sim=c@c^T --------
__global__ __launch_bounds__(256) void gemm_concepts(
    const ushort* __restrict__ cbf, const ushort* __restrict__ WkT,
    ushort* __restrict__ kmat, float* __restrict__ sim)
{
    __shared__ alignas(16) ushort As[128 * 32];
    __shared__ alignas(16) ushort Bs[128 * 32];
    const int K = 1024;
    const int id = threadIdx.x;
    const int wave = id >> 6, lane = id & 63;
    const bool issim = blockIdx.x >= 8;
    const ushort* B = issim ? cbf : WkT;
    const int col0 = (issim ? (int)blockIdx.x - 8 : (int)blockIdx.x) * 128;
    const int row0 = blockIdx.y * 128;
    const int wm = (wave >> 1) * 64, wn = (wave & 1) * 64;

    const int f0 = id, f1 = id + 256;
    const int ar0 = f0 >> 2, as0 = (f0 & 3) * 8;
    const int ar1 = f1 >> 2, as1 = (f1 & 3) * 8;

    const ushort* Ag0 = cbf + (size_t)(row0 + ar0) * K + as0;
    const ushort* Ag1 = cbf + (size_t)(row0 + ar1) * K + as1;
    const ushort* Bg0 = B + (size_t)(col0 + ar0) * K + as0;
    const ushort* Bg1 = B + (size_t)(col0 + ar1) * K + as1;

    floatx4 acc[4][4] = {};
    const int mrow = lane & 15, koff = (lane >> 4) * 8;

    for (int k0 = 0; k0 < K; k0 += 32) {
        gl_lds16(Ag0 + k0, &As[f0 * 8]);
        gl_lds16(Ag1 + k0, &As[f1 * 8]);
        gl_lds16(Bg0 + k0, &Bs[f0 * 8]);
        gl_lds16(Bg1 + k0, &Bs[f1 * 8]);
        __syncthreads();
        short8 a[4], b[4];
        #pragma unroll
        for (int i = 0; i < 4; i++)
            a[i] = *(const short8*)&As[(wm + i * 16 + mrow) * 32 + koff];
        #pragma unroll
        for (int j = 0; j < 4; j++)
            b[j] = *(const short8*)&Bs[(wn + j * 16 + mrow) * 32 + koff];
        #pragma unroll
        for (int i = 0; i < 4; i++)
            #pragma unroll
            for (int j = 0; j < 4; j++)
                acc[i][j] = __builtin_amdgcn_mfma_f32_16x16x32_bf16(a[i], b[j], acc[i][j], 0, 0, 0);
        __syncthreads();
    }

    const int ccol0 = col0 + wn + (lane & 15);
    const int crow0 = row0 + wm + (lane >> 4) * 4;
    #pragma unroll
    for (int i = 0; i < 4; i++)
        #pragma unroll
        for (int r = 0; r < 4; r++) {
            const int row = crow0 + i * 16 + r;
            #pragma unroll
            for (int j = 0; j < 4; j++) {
                int col = ccol0 + j * 16;
                float v = acc[i][j][r];
                if (issim) sim[(size_t)row * 512 + col] = v;
                else       kmat[(size_t)row * 1024 + col] = f2b(v);
            }
        }
}

// =============== MX-fp8 MFMA GEMM (fc layer): out = (1/16)*acc*rsqrt(rn) + bias =====
__global__ __launch_bounds__(256) void gemm_f8_fc(
    const uint8_t* __restrict__ A, const uint8_t* __restrict__ B,
    const float* __restrict__ bias, const float* __restrict__ rn,
    float* __restrict__ C, int M, int N, int K, float scale)
{
    __shared__ alignas(16) uint8_t As[128 * 128];
    __shared__ alignas(16) uint8_t Bs[128 * 128];
    const int id = threadIdx.x;
    const int wave = id >> 6, lane = id & 63;

    int bxi = blockIdx.x, byi = blockIdx.y;
    if ((gridDim.y & 7) == 0) {
        int i = byi * gridDim.x + bxi;
        int xcd = i & 7;
        int j = i >> 3;
        bxi = j % gridDim.x;
        byi = xcd + 8 * (j / gridDim.x);
    }
    const int row0 = byi * 128, col0 = bxi * 128;
    const int wm = (wave >> 1) * 64, wn = (wave & 1) * 64;

    const int fr = id >> 3;
    const int fss = (id & 7) ^ (fr & 7);
    const size_t tstride = (size_t)32 * K;
    const uint8_t* Ag = A + (size_t)(row0 + fr) * K + fss * 16;
    const uint8_t* Bgp[4];
    #pragma unroll
    for (int t = 0; t < 4; t++)
        Bgp[t] = B + (size_t)min(col0 + fr + 32 * t, N - 1) * K + fss * 16;

    floatx4 acc[4][4] = {};
    const int mrow = lane & 15;
    const int g2 = (lane >> 4) * 2;

    for (int k0 = 0; k0 < K; k0 += 128) {
        #pragma unroll
        for (int t = 0; t < 4; t++) {
            gl_lds16(Ag + k0 + tstride * t, &As[id * 16 + 4096 * t]);
            gl_lds16(Bgp[t] + k0, &Bs[id * 16 + 4096 * t]);
        }
        __syncthreads();
        int8v a[4], b[4];
        #pragma unroll
        for (int i = 0; i < 4; i++) {
            int r = wm + i * 16 + mrow, rs = r & 7;
            int4v lo = *(const int4v*)&As[r * 128 + ((g2    ) ^ rs) * 16];
            int4v hi = *(const int4v*)&As[r * 128 + ((g2 + 1) ^ rs) * 16];
            a[i] = __builtin_shufflevector(lo, hi, 0, 1, 2, 3, 4, 5, 6, 7);
        }
        #pragma unroll
        for (int j = 0; j < 4; j++) {
            int r = wn + j * 16 + mrow, rs = r & 7;
            int4v lo = *(const int4v*)&Bs[r * 128 + ((g2    ) ^ rs) * 16];
            int4v hi = *(const int4v*)&Bs[r * 128 + ((g2 + 1) ^ rs) * 16];
            b[j] = __builtin_shufflevector(lo, hi, 0, 1, 2, 3, 4, 5, 6, 7);
        }
        #pragma unroll
        for (int i = 0; i < 4; i++)
            #pragma unroll
            for (int j = 0; j < 4; j++)
                acc[i][j] = __builtin_amdgcn_mfma_scale_f32_16x16x128_f8f6f4(
                    a[i], b[j], acc[i][j], 0, 0, 0, 0x7f7f7f7f, 0, 0x7f7f7f7f);
        __syncthreads();
    }

    const int ccol0 = col0 + wn + (lane & 15);
    const int crow0 = row0 + wm + (lane >> 4) * 4;
    float bv[4];
    #pragma unroll
    for (int j = 0; j < 4; j++) {
        int col = ccol0 + j * 16;
        bv[j] = (col < N) ? bias[col] : 0.0f;
    }
    #pragma unroll
    for (int i = 0; i < 4; i++) {
        #pragma unroll
        for (int r = 0; r < 4; r++) {
            const int row = crow0 + i * 16 + r;
            float inv = rsqrtf(rn[row]);
            #pragma unroll
            for (int j = 0; j < 4; j++) {
                int col = ccol0 + j * 16;
                if (col < N)
                    C[(size_t)row * N + col] = acc[i][j][r] * scale * inv + bv[j];
            }
        }
    }
}

// --- sparsemax rows of 512: bf16 scores in -> f32 attn (d_out) + bf16 copy ---------
__global__ __launch_bounds__(256) void sparsemax_k(const ushort* __restrict__ Sb,
                                                   float* __restrict__ attn,
                                                   ushort* __restrict__ Ab) {
    int wave = threadIdx.x >> 6, lane = threadIdx.x & 63;
    int row = blockIdx.x * 4 + wave;
    const ushort* z = Sb + (size_t)row * 512;
    float v[8];
    #pragma unroll
    for (int j = 0; j < 8; j++) v[j] = b2f(z[lane + 64 * j]);
    float mx = v[0];
    #pragma unroll
    for (int j = 1; j < 8; j++) mx = fmaxf(mx, v[j]);
    #pragma unroll
    for (int off = 1; off < 64; off <<= 1) mx = fmaxf(mx, __shfl_xor(mx, off, 64));
    float lo = mx - 1.0f, hi = mx;
    for (int it = 0; it < 30; it++) {
        float tau = 0.5f * (lo + hi);
        float s = 0.0f;
        #pragma unroll
        for (int j = 0; j < 8; j++) s += fmaxf(v[j] - tau, 0.0f);
        #pragma unroll
        for (int off = 1; off < 64; off <<= 1) s += __shfl_xor(s, off, 64);
        if (s >= 1.0f) lo = tau; else hi = tau;
    }
    float tau = 0.5f * (lo + hi);
    float* of = attn + (size_t)row * 512;
    ushort* ob = Ab + (size_t)row * 512;
    #pragma unroll
    for (int j = 0; j < 8; j++) {
        float o = fmaxf(v[j] - tau, 0.0f);
        of[lane + 64 * j] = o;
        ob[lane + 64 * j] = f2b(o);
    }
}

extern "C" void kernel_launch(void* const* d_in, const int* in_sizes, int n_in,
                              void* d_out, int out_size, void* d_ws, size_t ws_size,
                              hipStream_t stream) {
    const float* x        = (const float*)d_in[0];
    const float* concepts = (const float*)d_in[1];
    const float* Wq       = (const float*)d_in[2];
    const float* Wk       = (const float*)d_in[3];
    const float* fc_w     = (const float*)d_in[4];
    const float* fc_b     = (const float*)d_in[5];

    const int B = 16384, D = 1024, C = 512, N = 1000;

    float* out  = (float*)d_out;                       // [B,N]
    float* attn = out + (size_t)B * N;                 // [B,C]
    float* sim  = attn + (size_t)B * C;                // [C,C]

    // ---- ws layout (~58 MiB; overlapped lifetimes disjoint in time) ----
    uint8_t* w = (uint8_t*)d_ws;
    ushort*  x_bf     = (ushort*)w;                     // [B,D] bf16 32 MiB (dead after scores)
    ushort*  attn_bf  = (ushort*)w;                     // [B,C] bf16 16 MiB (after x dead)
    ushort*  score_bf = (ushort*)(w + (32ull << 20));   // [B,C] bf16 16 MiB (dead after sparsemax)
    uint8_t* summ_f8  = w + (32ull << 20);              // [B,D] fp8  16 MiB (after scores dead)
    ushort*  Wq_bf    = (ushort*)(w + (48ull << 20));   // [D,D] bf16  2 MiB
    ushort*  WkT_bf   = (ushort*)(w + (50ull << 20));   // [D,D] bf16  2 MiB
    ushort*  c_bf     = (ushort*)(w + (52ull << 20));   // [C,D] bf16  1 MiB
    ushort*  cT_bf    = (ushort*)(w + (53ull << 20));   // [D,C] bf16  1 MiB
    ushort*  kmat_bf  = (ushort*)(w + (54ull << 20));   // [C,D] bf16  1 MiB
    ushort*  PT_bf    = (ushort*)(w + (55ull << 20));   // [C,D] bf16  1 MiB
    uint8_t* fcw_f8   = w + (56ull << 20);              // [N,D] fp8   1 MiB
    float*   rn       = (float*)(w + (57ull << 20));    // [B]        64 KiB

    // 1. prep conversions
    convert_f32_bf16<<<(B * D / 4 + 255) / 256, 256, 0, stream>>>(x, x_bf, B * D / 4);
    convert_f32_bf16<<<(D * D / 4 + 255) / 256, 256, 0, stream>>>(Wq, Wq_bf, D * D / 4);
    normalize_f32_to_bf16<<<C, 256, 0, stream>>>(concepts, c_bf, D);
    transpose_f32_to_bf16<<<dim3(D / 32, D / 32), 256, 0, stream>>>(Wk, WkT_bf, D, D);
    transpose_bf16<<<dim3(D / 32, C / 32), 256, 0, stream>>>(c_bf, cT_bf, C, D);
    convert_f32_fp8<<<(N * D / 4 + 255) / 256, 256, 0, stream>>>(fc_w, fcw_f8, N * D / 4, 16.0f);
    // 2. kmat = c @ Wk^T (bf16), sim = c @ c^T (f32 -> d_out)
    gemm_concepts<<<dim3(12, C / 128), 256, 0, stream>>>(c_bf, WkT_bf, kmat_bf, sim);
    // 3. PT = k @ Wq^T  [C,D]  (the q-GEMM eliminator: scores = x @ PT^T)
    gemm_bt<0><<<dim3(D / 128, C / 128), 256, 0, stream>>>(
        kmat_bf, Wq_bf, nullptr, PT_bf, C, D, D, 1.0f);
    // 4. scores = (x @ PT^T)/32 -> bf16
    gemm_bt<0><<<dim3(C / 128, B / 128), 256, 0, stream>>>(
        x_bf, PT_bf, nullptr, score_bf, B, C, D, 0.03125f);
    // 5. sparsemax: scores -> f32 attn (d_out) + bf16 copy (x region now dead)
    sparsemax_k<<<B / 4, 256, 0, stream>>>(score_bf, attn, attn_bf);
    // 6. summary = attn @ c (bf16 MFMA), epilogue: fp8(*64) out + rn sumsq
    hipMemsetAsync(rn, 0, B * sizeof(float), stream);
    gemm_bt<1><<<dim3(D / 128, B / 128), 256, 0, stream>>>(
        attn_bf, cT_bf, rn, summ_f8, B, D, C, 1.0f);
    // 7. out = (summ/||summ||) @ fc_w^T + fc_b   (64 and 16 scales fold: 1/16 * rsqrt)
    gemm_f8_fc<<<dim3((N + 127) / 128, B / 128), 256, 0, stream>>>(
        summ_f8, fcw_f8, fc_b, rn, out, B, N, D, 1.0f / 16.0f);
}

// Round 7
// 332.804 us; speedup vs baseline: 1.0172x; 1.0172x over previous
//
#include <hip/hip_runtime.h>
#include <hip/hip_bf16.h>
#include <stdint.h>

typedef __attribute__((ext_vector_type(8))) short short8;
typedef __attribute__((ext_vector_type(4))) float floatx4;
typedef __attribute__((ext_vector_type(8))) int int8v;
typedef __attribute__((ext_vector_type(4))) int int4v;

__device__ __forceinline__ ushort f2b(float f) {
    union { float f; uint32_t u; } v; v.f = f;
    uint32_t r = (v.u + 0x7fffu + ((v.u >> 16) & 1u)) >> 16;
    return (ushort)r;
}
__device__ __forceinline__ float b2f(ushort b) {
    union { uint32_t u; float f; } v; v.u = ((uint32_t)b) << 16;
    return v.f;
}
__device__ __forceinline__ uint8_t f2fp8(float f) {
    return (uint8_t)(__builtin_amdgcn_cvt_pk_fp8_f32(f, f, 0, false) & 0xff);
}

__device__ __forceinline__ void gl_lds16(const void* g, void* l) {
    __builtin_amdgcn_global_load_lds(
        (const __attribute__((address_space(1))) void*)g,
        (__attribute__((address_space(3))) void*)l, 16, 0, 0);
}

// ================= fused prep: all input conversions in ONE kernel =================
// block ranges:
//   [0,16384)        x f32 -> bf16            (B*D/4 = 16384*256 float4s)
//   [16384,17408)    Wq f32 -> bf16           (D*D/4 = 1024*256)
//   [17408,18432)    Wk f32 -> bf16
//   [18432,19432)    fc_w f32 -> fp8*16       (N*D/4 = 1000*256)
//   [19432,19944)    c = normalize(concepts) -> c_bf row + cT scatter
//   [19944,19960)    rn = 0                   (B/4 = 16*256 float4s)
#define PREP_BLOCKS 19960
__global__ __launch_bounds__(256) void prep_all(
    const float* __restrict__ x, const float* __restrict__ Wq,
    const float* __restrict__ Wk, const float* __restrict__ concepts,
    const float* __restrict__ fc_w,
    ushort* __restrict__ x_bf, ushort* __restrict__ Wq_bf, ushort* __restrict__ Wk_bf,
    ushort* __restrict__ c_bf, ushort* __restrict__ cT_bf,
    uint8_t* __restrict__ fcw_f8, float* __restrict__ rn)
{
    const int b = blockIdx.x, tid = threadIdx.x;
    if (b < 16384) {                     // x convert
        int i = b * 256 + tid;
        float4 v = ((const float4*)x)[i];
        ushort4 o; o.x = f2b(v.x); o.y = f2b(v.y); o.z = f2b(v.z); o.w = f2b(v.w);
        ((ushort4*)x_bf)[i] = o;
    } else if (b < 18432) {              // Wq / Wk convert
        int i = (b - 16384) * 256 + tid;             // 0 .. 2*262144
        const float* src = (i < 262144) ? Wq : Wk;
        ushort* dst = (i < 262144) ? Wq_bf : Wk_bf;
        int j = i & 262143;
        float4 v = ((const float4*)src)[j];
        ushort4 o; o.x = f2b(v.x); o.y = f2b(v.y); o.z = f2b(v.z); o.w = f2b(v.w);
        ((ushort4*)dst)[j] = o;
    } else if (b < 19432) {              // fc_w -> fp8 * 16
        int i = (b - 18432) * 256 + tid;
        float4 v = ((const float4*)fc_w)[i];
        int p = __builtin_amdgcn_cvt_pk_fp8_f32(v.x * 16.0f, v.y * 16.0f, 0, false);
        p = __builtin_amdgcn_cvt_pk_fp8_f32(v.z * 16.0f, v.w * 16.0f, p, true);
        ((uint32_t*)fcw_f8)[i] = p;
    } else if (b < 19944) {              // normalize concept row + cT scatter
        int row = b - 19432;
        float4 v = ((const float4*)(concepts + (size_t)row * 1024))[tid];
        float s = v.x * v.x + v.y * v.y + v.z * v.z + v.w * v.w;
        __shared__ float sm[4];
        #pragma unroll
        for (int off = 32; off; off >>= 1) s += __shfl_down(s, off, 64);
        if ((tid & 63) == 0) sm[tid >> 6] = s;
        __syncthreads();
        float inv = 1.0f / sqrtf(sm[0] + sm[1] + sm[2] + sm[3]);
        float c0 = v.x * inv, c1 = v.y * inv, c2 = v.z * inv, c3 = v.w * inv;
        ushort4 o; o.x = f2b(c0); o.y = f2b(c1); o.z = f2b(c2); o.w = f2b(c3);
        ((ushort4*)(c_bf + (size_t)row * 1024))[tid] = o;
        int d = tid * 4;
        cT_bf[(size_t)(d + 0) * 512 + row] = o.x;
        cT_bf[(size_t)(d + 1) * 512 + row] = o.y;
        cT_bf[(size_t)(d + 2) * 512 + row] = o.z;
        cT_bf[(size_t)(d + 3) * 512 + row] = o.w;
    } else {                             // rn = 0
        int i = (b - 19944) * 256 + tid;
        ((float4*)rn)[i] = make_float4(0.f, 0.f, 0.f, 0.f);
    }
}

// ======== bf16 MFMA GEMM core (m97 structure), templated epilogue ========
// MODE 0: bf16 out = scale*acc      MODE 1: fp8 out = f2fp8(64*acc) + rn sumsq atomic
template<int MODE>
__global__ __launch_bounds__(256, 4) void gemm_bt(
    const ushort* __restrict__ A, const ushort* __restrict__ B,
    float* __restrict__ rn, void* __restrict__ Co,
    int M, int N, int K, float scale)
{
    __shared__ alignas(16) ushort As[128 * 32];
    __shared__ alignas(16) ushort Bs[128 * 32];
    const int id = threadIdx.x;
    const int wave = id >> 6, lane = id & 63;

    int bxi = blockIdx.x, byi = blockIdx.y;
    if ((gridDim.y & 7) == 0) {
        int i = byi * gridDim.x + bxi;
        int xcd = i & 7;
        int j = i >> 3;
        bxi = j % gridDim.x;
        byi = xcd + 8 * (j / gridDim.x);
    }
    const int row0 = byi * 128, col0 = bxi * 128;
    const int wm = (wave >> 1) * 64, wn = (wave & 1) * 64;

    const int f0 = id, f1 = id + 256;
    const int ar0 = f0 >> 2, as0 = (f0 & 3) * 8;
    const int ar1 = f1 >> 2, as1 = (f1 & 3) * 8;

    const ushort* Ag0 = A + (size_t)(row0 + ar0) * K + as0;
    const ushort* Ag1 = A + (size_t)(row0 + ar1) * K + as1;
    const ushort* Bg0 = B + (size_t)(col0 + ar0) * K + as0;
    const ushort* Bg1 = B + (size_t)(col0 + ar1) * K + as1;

    floatx4 acc[4][4] = {};
    const int mrow = lane & 15, koff = (lane >> 4) * 8;

    for (int k0 = 0; k0 < K; k0 += 32) {
        gl_lds16(Ag0 + k0, &As[f0 * 8]);
        gl_lds16(Ag1 + k0, &As[f1 * 8]);
        gl_lds16(Bg0 + k0, &Bs[f0 * 8]);
        gl_lds16(Bg1 + k0, &Bs[f1 * 8]);
        __syncthreads();
        short8 a[4], b[4];
        #pragma unroll
        for (int i = 0; i < 4; i++)
            a[i] = *(const short8*)&As[(wm + i * 16 + mrow) * 32 + koff];
        #pragma unroll
        for (int j = 0; j < 4; j++)
            b[j] = *(const short8*)&Bs[(wn + j * 16 + mrow) * 32 + koff];
        #pragma unroll
        for (int i = 0; i < 4; i++)
            #pragma unroll
            for (int j = 0; j < 4; j++)
                acc[i][j] = __builtin_amdgcn_mfma_f32_16x16x32_bf16(a[i], b[j], acc[i][j], 0, 0, 0);
        __syncthreads();
    }

    // C/D layout: col = lane&15, row = (lane>>4)*4 + r  [m89/m91-verified]
    const int ccol0 = col0 + wn + (lane & 15);
    const int crow0 = row0 + wm + (lane >> 4) * 4;
    #pragma unroll
    for (int i = 0; i < 4; i++) {
        #pragma unroll
        for (int r = 0; r < 4; r++) {
            const int row = crow0 + i * 16 + r;
            float ss = 0.0f;
            #pragma unroll
            for (int j = 0; j < 4; j++) {
                int col = ccol0 + j * 16;
                if constexpr (MODE == 0) {
                    ((ushort*)Co)[(size_t)row * N + col] = f2b(acc[i][j][r] * scale);
                } else {
                    float vq = acc[i][j][r] * 64.0f;     // store 64*summary (fp8)
                    ss += vq * vq;
                    ((uint8_t*)Co)[(size_t)row * N + col] = f2fp8(vq);
                }
            }
            if constexpr (MODE == 1) {
                #pragma unroll
                for (int m = 1; m < 16; m <<= 1) ss += __shfl_xor(ss, m, 64);
                if ((lane & 15) == 0) atomicAdd(&rn[row], ss);
            }
        }
    }
}

// ---- fused concept GEMMs: PT = c@W2^T-row-major-B (bf16 out), sim = c@c^T (f32) ----
// grid (12,4): bx<8 -> PT cols (B=W2), bx>=8 -> sim cols (B=c). K=1024 both.
__global__ __launch_bounds__(256) void gemm_concepts(
    const ushort* __restrict__ cbf, const ushort* __restrict__ W2,
    ushort* __restrict__ PT, float* __restrict__ sim)
{
    __shared__ alignas(16) ushort As[128 * 32];
    __shared__ alignas(16) ushort Bs[128 * 32];
    const int K = 1024;
    const int id = threadIdx.x;
    const int wave = id >> 6, lane = id & 63;
    const bool issim = blockIdx.x >= 8;
    const ushort* B = issim ? cbf : W2;
    const int col0 = (issim ? (int)blockIdx.x - 8 : (int)blockIdx.x) * 128;
    const int row0 = blockIdx.y * 128;
    const int wm = (wave >> 1) * 64, wn = (wave & 1) * 64;

    const int f0 = id, f1 = id + 256;
    const int ar0 = f0 >> 2, as0 = (f0 & 3) * 8;
    const int ar1 = f1 >> 2, as1 = (f1 & 3) * 8;

    const ushort* Ag0 = cbf + (size_t)(row0 + ar0) * K + as0;
    const ushort* Ag1 = cbf + (size_t)(row0 + ar1) * K + as1;
    const ushort* Bg0 = B + (size_t)(col0 + ar0) * K + as0;
    const ushort* Bg1 = B + (size_t)(col0 + ar1) * K + as1;

    floatx4 acc[4][4] = {};
    const int mrow = lane & 15, koff = (lane >> 4) * 8;

    for (int k0 = 0; k0 < K; k0 += 32) {
        gl_lds16(Ag0 + k0, &As[f0 * 8]);
        gl_lds16(Ag1 + k0, &As[f1 * 8]);
        gl_lds16(Bg0 + k0, &Bs[f0 * 8]);
        gl_lds16(Bg1 + k0, &Bs[f1 * 8]);
        __syncthreads();
        short8 a[4], b[4];
        #pragma unroll
        for (int i = 0; i < 4; i++)
            a[i] = *(const short8*)&As[(wm + i * 16 + mrow) * 32 + koff];
        #pragma unroll
        for (int j = 0; j < 4; j++)
            b[j] = *(const short8*)&Bs[(wn + j * 16 + mrow) * 32 + koff];
        #pragma unroll
        for (int i = 0; i < 4; i++)
            #pragma unroll
            for (int j = 0; j < 4; j++)
                acc[i][j] = __builtin_amdgcn_mfma_f32_16x16x32_bf16(a[i], b[j], acc[i][j], 0, 0, 0);
        __syncthreads();
    }

    const int ccol0 = col0 + wn + (lane & 15);
    const int crow0 = row0 + wm + (lane >> 4) * 4;
    #pragma unroll
    for (int i = 0; i < 4; i++)
        #pragma unroll
        for (int r = 0; r < 4; r++) {
            const int row = crow0 + i * 16 + r;
            #pragma unroll
            for (int j = 0; j < 4; j++) {
                int col = ccol0 + j * 16;
                float v = acc[i][j][r];
                if (issim) sim[(size_t)row * 512 + col] = v;
                else       PT[(size_t)row * 1024 + col] = f2b(v);
            }
        }
}

// =============== MX-fp8 MFMA GEMM (fc layer): out = (1/16)*acc*rsqrt(rn) + bias =====
__global__ __launch_bounds__(256) void gemm_f8_fc(
    const uint8_t* __restrict__ A, const uint8_t* __restrict__ B,
    const float* __restrict__ bias, const float* __restrict__ rn,
    float* __restrict__ C, int M, int N, int K, float scale)
{
    __shared__ alignas(16) uint8_t As[128 * 128];
    __shared__ alignas(16) uint8_t Bs[128 * 128];
    const int id = threadIdx.x;
    const int wave = id >> 6, lane = id & 63;

    int bxi = blockIdx.x, byi = blockIdx.y;
    if ((gridDim.y & 7) == 0) {
        int i = byi * gridDim.x + bxi;
        int xcd = i & 7;
        int j = i >> 3;
        bxi = j % gridDim.x;
        byi = xcd + 8 * (j / gridDim.x);
    }
    const int row0 = byi * 128, col0 = bxi * 128;
    const int wm = (wave >> 1) * 64, wn = (wave & 1) * 64;

    const int fr = id >> 3;
    const int fss = (id & 7) ^ (fr & 7);
    const size_t tstride = (size_t)32 * K;
    const uint8_t* Ag = A + (size_t)(row0 + fr) * K + fss * 16;
    const uint8_t* Bgp[4];
    #pragma unroll
    for (int t = 0; t < 4; t++)
        Bgp[t] = B + (size_t)min(col0 + fr + 32 * t, N - 1) * K + fss * 16;

    floatx4 acc[4][4] = {};
    const int mrow = lane & 15;
    const int g2 = (lane >> 4) * 2;

    for (int k0 = 0; k0 < K; k0 += 128) {
        #pragma unroll
        for (int t = 0; t < 4; t++) {
            gl_lds16(Ag + k0 + tstride * t, &As[id * 16 + 4096 * t]);
            gl_lds16(Bgp[t] + k0, &Bs[id * 16 + 4096 * t]);
        }
        __syncthreads();
        int8v a[4], b[4];
        #pragma unroll
        for (int i = 0; i < 4; i++) {
            int r = wm + i * 16 + mrow, rs = r & 7;
            int4v lo = *(const int4v*)&As[r * 128 + ((g2    ) ^ rs) * 16];
            int4v hi = *(const int4v*)&As[r * 128 + ((g2 + 1) ^ rs) * 16];
            a[i] = __builtin_shufflevector(lo, hi, 0, 1, 2, 3, 4, 5, 6, 7);
        }
        #pragma unroll
        for (int j = 0; j < 4; j++) {
            int r = wn + j * 16 + mrow, rs = r & 7;
            int4v lo = *(const int4v*)&Bs[r * 128 + ((g2    ) ^ rs) * 16];
            int4v hi = *(const int4v*)&Bs[r * 128 + ((g2 + 1) ^ rs) * 16];
            b[j] = __builtin_shufflevector(lo, hi, 0, 1, 2, 3, 4, 5, 6, 7);
        }
        #pragma unroll
        for (int i = 0; i < 4; i++)
            #pragma unroll
            for (int j = 0; j < 4; j++)
                acc[i][j] = __builtin_amdgcn_mfma_scale_f32_16x16x128_f8f6f4(
                    a[i], b[j], acc[i][j], 0, 0, 0, 0x7f7f7f7f, 0, 0x7f7f7f7f);
        __syncthreads();
    }

    const int ccol0 = col0 + wn + (lane & 15);
    const int crow0 = row0 + wm + (lane >> 4) * 4;
    float bv[4];
    #pragma unroll
    for (int j = 0; j < 4; j++) {
        int col = ccol0 + j * 16;
        bv[j] = (col < N) ? bias[col] : 0.0f;
    }
    #pragma unroll
    for (int i = 0; i < 4; i++) {
        #pragma unroll
        for (int r = 0; r < 4; r++) {
            const int row = crow0 + i * 16 + r;
            float inv = rsqrtf(rn[row]);
            #pragma unroll
            for (int j = 0; j < 4; j++) {
                int col = ccol0 + j * 16;
                if (col < N)
                    C[(size_t)row * N + col] = acc[i][j][r] * scale * inv + bv[j];
            }
        }
    }
}

// --- sparsemax rows of 512: bf16 scores in -> f32 attn (d_out) + bf16 copy ---------
__global__ __launch_bounds__(256) void sparsemax_k(const ushort* __restrict__ Sb,
                                                   float* __restrict__ attn,
                                                   ushort* __restrict__ Ab) {
    int wave = threadIdx.x >> 6, lane = threadIdx.x & 63;
    int row = blockIdx.x * 4 + wave;
    const ushort* z = Sb + (size_t)row * 512;
    float v[8];
    #pragma unroll
    for (int j = 0; j < 8; j++) v[j] = b2f(z[lane + 64 * j]);
    float mx = v[0];
    #pragma unroll
    for (int j = 1; j < 8; j++) mx = fmaxf(mx, v[j]);
    #pragma unroll
    for (int off = 1; off < 64; off <<= 1) mx = fmaxf(mx, __shfl_xor(mx, off, 64));
    float lo = mx - 1.0f, hi = mx;
    for (int it = 0; it < 30; it++) {
        float tau = 0.5f * (lo + hi);
        float s = 0.0f;
        #pragma unroll
        for (int j = 0; j < 8; j++) s += fmaxf(v[j] - tau, 0.0f);
        #pragma unroll
        for (int off = 1; off < 64; off <<= 1) s += __shfl_xor(s, off, 64);
        if (s >= 1.0f) lo = tau; else hi = tau;
    }
    float tau = 0.5f * (lo + hi);
    float* of = attn + (size_t)row * 512;
    ushort* ob = Ab + (size_t)row * 512;
    #pragma unroll
    for (int j = 0; j < 8; j++) {
        float o = fmaxf(v[j] - tau, 0.0f);
        of[lane + 64 * j] = o;
        ob[lane + 64 * j] = f2b(o);
    }
}

extern "C" void kernel_launch(void* const* d_in, const int* in_sizes, int n_in,
                              void* d_out, int out_size, void* d_ws, size_t ws_size,
                              hipStream_t stream) {
    const float* x        = (const float*)d_in[0];
    const float* concepts = (const float*)d_in[1];
    const float* Wq       = (const float*)d_in[2];
    const float* Wk       = (const float*)d_in[3];
    const float* fc_w     = (const float*)d_in[4];
    const float* fc_b     = (const float*)d_in[5];

    const int B = 16384, D = 1024, C = 512, N = 1000;

    float* out  = (float*)d_out;                       // [B,N]
    float* attn = out + (size_t)B * N;                 // [B,C]
    float* sim  = attn + (size_t)B * C;                // [C,C]

    // ---- ws layout (~59 MiB; overlapped lifetimes disjoint in time) ----
    uint8_t* w = (uint8_t*)d_ws;
    ushort*  x_bf     = (ushort*)w;                     // [B,D] bf16 32 MiB (dead after scores)
    ushort*  attn_bf  = (ushort*)w;                     // [B,C] bf16 16 MiB (after x dead)
    ushort*  score_bf = (ushort*)(w + (32ull << 20));   // [B,C] bf16 16 MiB (dead after sparsemax)
    uint8_t* summ_f8  = w + (32ull << 20);              // [B,D] fp8  16 MiB (after scores dead)
    ushort*  Wq_bf    = (ushort*)(w + (48ull << 20));   // [D,D] bf16  2 MiB
    ushort*  Wk_bf    = (ushort*)(w + (50ull << 20));   // [D,D] bf16  2 MiB
    ushort*  c_bf     = (ushort*)(w + (52ull << 20));   // [C,D] bf16  1 MiB
    ushort*  cT_bf    = (ushort*)(w + (53ull << 20));   // [D,C] bf16  1 MiB
    ushort*  W2_bf    = (ushort*)(w + (54ull << 20));   // [D,D] bf16  2 MiB
    ushort*  PT_bf    = (ushort*)(w + (56ull << 20));   // [C,D] bf16  1 MiB
    uint8_t* fcw_f8   = w + (57ull << 20);              // [N,D] fp8   1 MiB
    float*   rn       = (float*)(w + (58ull << 20));    // [B]        64 KiB

    // 1. all conversions + concept normalize + cT + rn=0, ONE kernel
    prep_all<<<PREP_BLOCKS, 256, 0, stream>>>(
        x, Wq, Wk, concepts, fc_w, x_bf, Wq_bf, Wk_bf, c_bf, cT_bf, fcw_f8, rn);
    // 2. W2 = Wq @ Wk^T  [D,D]  (both operands row-major k-major -> no transposes)
    gemm_bt<0><<<dim3(D / 128, D / 128), 256, 0, stream>>>(
        Wq_bf, Wk_bf, nullptr, W2_bf, D, D, D, 1.0f);
    // 3. PT = c @ W2^T-form  [C,D] (B-operand = W2 row-major) ; sim = c @ c^T -> d_out
    gemm_concepts<<<dim3(12, C / 128), 256, 0, stream>>>(c_bf, W2_bf, PT_bf, sim);
    // 4. scores = (x @ PT^T)/32 -> bf16   (== x @ Wq @ Wk^T @ c^T / 32)
    gemm_bt<0><<<dim3(C / 128, B / 128), 256, 0, stream>>>(
        x_bf, PT_bf, nullptr, score_bf, B, C, D, 0.03125f);
    // 5. sparsemax: scores -> f32 attn (d_out) + bf16 copy (x region now dead)
    sparsemax_k<<<B / 4, 256, 0, stream>>>(score_bf, attn, attn_bf);
    // 6. summary = attn @ c (bf16 MFMA), epilogue: fp8(*64) out + rn sumsq
    gemm_bt<1><<<dim3(D / 128, B / 128), 256, 0, stream>>>(
        attn_bf, cT_bf, rn, summ_f8, B, D, C, 1.0f);
    // 7. out = (summ/||summ||) @ fc_w^T + fc_b   (64/16 scales fold into 1/16*rsqrt)
    gemm_f8_fc<<<dim3((N + 127) / 128, B / 128), 256, 0, stream>>>(
        summ_f8, fcw_f8, fc_b, rn, out, B, N, D, 1.0f / 16.0f);
}